// Round 2
// baseline (650.591 us; speedup 1.0000x reference)
//
#include <hip/hip_runtime.h>

typedef __attribute__((ext_vector_type(4))) float f32x4;
typedef __attribute__((ext_vector_type(8))) short s16x8;
typedef __attribute__((ext_vector_type(4))) short s16x4;

// B=2048 windows, N=64 tokens, C=256, H=32 heads, d=8
#define NWIN 2048

__device__ __forceinline__ ushort f2bf(float f) {
    union { float f; unsigned u; } v; v.f = f;
    unsigned r = v.u + 0x7FFFu + ((v.u >> 16) & 1u);   // RNE
    return (ushort)(r >> 16);
}
__device__ __forceinline__ float bf2f(ushort u) {
    union { unsigned u; float f; } v; v.u = ((unsigned)u) << 16;
    return v.f;
}
__device__ __forceinline__ unsigned pk2(float a, float b) {
    return (unsigned)f2bf(a) | ((unsigned)f2bf(b) << 16);
}
union BF4 { unsigned u[2]; s16x4 v; };

// ---- prep: weights -> bf16, bias_table gather -> bias[h][q][k] bf16 ----
__global__ void prep_kernel(const float* __restrict__ wqkv,
                            const float* __restrict__ wproj,
                            const float* __restrict__ btab,
                            ushort* __restrict__ wq,
                            ushort* __restrict__ wp,
                            ushort* __restrict__ bb) {
    int t = blockIdx.x * 256 + threadIdx.x;
    if (t < 196608) {                 // 768*256 w_qkv
        wq[t] = f2bf(wqkv[t]);
    } else if (t < 262144) {          // + 256*256 w_proj
        int i = t - 196608;
        wp[i] = f2bf(wproj[i]);
    } else if (t < 393216) {          // + 32*64*64 bias
        int i = t - 262144;
        int h  = i >> 12;
        int rem = i & 4095;
        int qi = rem >> 6;
        int kj = rem & 63;
        int rh = (qi >> 3) - (kj >> 3) + 7;
        int rw = (qi & 7)  - (kj & 7)  + 7;
        bb[i] = f2bf(btab[(rh * 15 + rw) * 32 + h]);
    }
}

// ---- fused, register-resident per-wave-heads version ----
// wave w owns heads 4w..4w+3. q/k computed transposed (W·x^T) so the
// accumulator layout (token=c, hd=4g+j) IS the attention fragment layout.
// Head selection within a 16-row (2-head) tile: zero one g-half of the
// Q (B) operand. V computed in original orientation = PV B-frag layout.
__global__ __launch_bounds__(512, 4) void attn_kernel(
    const float* __restrict__ x,
    const float* __restrict__ bqkv,
    const float* __restrict__ bproj,
    const ushort* __restrict__ wq,
    const ushort* __restrict__ wp,
    const ushort* __restrict__ biasb,
    float* __restrict__ out)
{
    __shared__ ushort sX[64 * 256];   // 32 KB: x bf16 (swizzled), later out_attn
    __shared__ float  sN[1024];       // 4 KB: [0,512) sum q^2 [tok][d]; [512,1024) k

    const int tid  = threadIdx.x;
    const int lane = tid & 63;
    const int w    = tid >> 6;
    const int g    = lane >> 4;
    const int c    = lane & 15;
    const int b    = blockIdx.x;

    const f32x4 fz = {0.f, 0.f, 0.f, 0.f};
    const s16x4 z4 = {0, 0, 0, 0};

    sN[tid] = 0.f; sN[tid + 512] = 0.f;

    // ---------- stage x -> bf16 LDS (row-XOR swizzled) ----------
    {
        const float4* xg = (const float4*)(x + (size_t)b * 16384);
        #pragma unroll
        for (int it = 0; it < 8; ++it) {
            int i = tid + it * 512;
            float4 v = xg[i];
            int row = i >> 6;
            int col = (i & 63) << 2;
            int bo = (row * 512 + col * 2) ^ ((row & 7) << 4);
            ushort4 u;
            u.x = f2bf(v.x); u.y = f2bf(v.y); u.z = f2bf(v.z); u.w = f2bf(v.w);
            *(ushort4*)((char*)sX + bo) = u;
        }
    }
    __syncthreads();

    // ---------- phase 2a: V GEMM (orig orientation), cols 512+32w..+32 ----------
    unsigned vpku[4][2][2];   // [token-tile][nv][2]  packed bf16, token=16kv+4g+j, d-col=c
    {
        f32x4 acc[4][2];
        #pragma unroll
        for (int mi = 0; mi < 4; ++mi) { acc[mi][0] = fz; acc[mi][1] = fz; }
        #pragma unroll
        for (int ks = 0; ks < 8; ++ks) {
            s16x8 af[4];
            #pragma unroll
            for (int mi = 0; mi < 4; ++mi) {
                int row = 16 * mi + c;
                int bo = (row * 512 + ks * 64 + g * 16) ^ ((row & 7) << 4);
                af[mi] = *(const s16x8*)((const char*)sX + bo);
            }
            s16x8 wv[2];
            #pragma unroll
            for (int nj = 0; nj < 2; ++nj)
                wv[nj] = *(const s16x8*)(wq + (512 + 32 * w + 16 * nj + c) * 256 + ks * 32 + g * 8);
            #pragma unroll
            for (int mi = 0; mi < 4; ++mi)
                #pragma unroll
                for (int nj = 0; nj < 2; ++nj)
                    acc[mi][nj] = __builtin_amdgcn_mfma_f32_16x16x32_bf16(af[mi], wv[nj], acc[mi][nj], 0, 0, 0);
        }
        float bv[2];
        bv[0] = bqkv[512 + 32 * w + c];
        bv[1] = bqkv[512 + 32 * w + 16 + c];
        #pragma unroll
        for (int mi = 0; mi < 4; ++mi)
            #pragma unroll
            for (int nj = 0; nj < 2; ++nj) {
                vpku[mi][nj][0] = pk2(acc[mi][nj][0] + bv[nj], acc[mi][nj][1] + bv[nj]);
                vpku[mi][nj][1] = pk2(acc[mi][nj][2] + bv[nj], acc[mi][nj][3] + bv[nj]);
            }
    }

    // ---------- phase 2b: Q,K transposed GEMM: D = W · x^T ----------
    f32x4 aq[2][4], ak[2][4];   // [hd-tile mt][token-tile nt]
    {
        #pragma unroll
        for (int mt = 0; mt < 2; ++mt)
            #pragma unroll
            for (int nt = 0; nt < 4; ++nt) { aq[mt][nt] = fz; ak[mt][nt] = fz; }
        #pragma unroll
        for (int ks = 0; ks < 8; ++ks) {
            s16x8 af[4];
            #pragma unroll
            for (int nt = 0; nt < 4; ++nt) {
                int row = 16 * nt + c;
                int bo = (row * 512 + ks * 64 + g * 16) ^ ((row & 7) << 4);
                af[nt] = *(const s16x8*)((const char*)sX + bo);
            }
            s16x8 wqa[2], wka[2];
            #pragma unroll
            for (int mt = 0; mt < 2; ++mt) {
                wqa[mt] = *(const s16x8*)(wq + (32 * w + 16 * mt + c) * 256 + ks * 32 + g * 8);
                wka[mt] = *(const s16x8*)(wq + (256 + 32 * w + 16 * mt + c) * 256 + ks * 32 + g * 8);
            }
            #pragma unroll
            for (int mt = 0; mt < 2; ++mt)
                #pragma unroll
                for (int nt = 0; nt < 4; ++nt) {
                    aq[mt][nt] = __builtin_amdgcn_mfma_f32_16x16x32_bf16(wqa[mt], af[nt], aq[mt][nt], 0, 0, 0);
                    ak[mt][nt] = __builtin_amdgcn_mfma_f32_16x16x32_bf16(wka[mt], af[nt], ak[mt][nt], 0, 0, 0);
                }
        }
        // + bias (per-lane: qkv-col = 32w + 16mt + 4g + j, indep of c/nt)
        f32x4 bq[2], bk[2];
        bq[0] = *(const f32x4*)(bqkv + 32 * w + 4 * g);
        bq[1] = *(const f32x4*)(bqkv + 32 * w + 16 + 4 * g);
        bk[0] = *(const f32x4*)(bqkv + 256 + 32 * w + 4 * g);
        bk[1] = *(const f32x4*)(bqkv + 256 + 32 * w + 16 + 4 * g);
        #pragma unroll
        for (int mt = 0; mt < 2; ++mt)
            #pragma unroll
            for (int nt = 0; nt < 4; ++nt) { aq[mt][nt] += bq[mt]; ak[mt][nt] += bk[mt]; }
        // head-axis norm partials: both mt (different heads) hit same (tok,d)
        #pragma unroll
        for (int nt = 0; nt < 4; ++nt)
            #pragma unroll
            for (int j = 0; j < 4; ++j) {
                int a = (16 * nt + c) * 8 + ((4 * g + j) & 7);
                atomicAdd(&sN[a],       aq[0][nt][j] * aq[0][nt][j] + aq[1][nt][j] * aq[1][nt][j]);
                atomicAdd(&sN[a + 512], ak[0][nt][j] * ak[0][nt][j] + ak[1][nt][j] * ak[1][nt][j]);
            }
    }
    __syncthreads();   // norms complete; all sX (x) reads complete

    // ---------- normalize + pack q/k to bf16 fragments ----------
    s16x4 qpk[2][4], kpk[2][4];
    #pragma unroll
    for (int nt = 0; nt < 4; ++nt) {
        float iq[4], ik[4];
        #pragma unroll
        for (int j = 0; j < 4; ++j) {
            int a = (16 * nt + c) * 8 + ((4 * g + j) & 7);
            iq[j] = 1.f / fmaxf(sqrtf(sN[a]), 1e-12f);
            ik[j] = 1.f / fmaxf(sqrtf(sN[a + 512]), 1e-12f);
        }
        #pragma unroll
        for (int mt = 0; mt < 2; ++mt) {
            BF4 uq, uk;
            uq.u[0] = pk2(aq[mt][nt][0] * iq[0], aq[mt][nt][1] * iq[1]);
            uq.u[1] = pk2(aq[mt][nt][2] * iq[2], aq[mt][nt][3] * iq[3]);
            uk.u[0] = pk2(ak[mt][nt][0] * ik[0], ak[mt][nt][1] * ik[1]);
            uk.u[1] = pk2(ak[mt][nt][2] * ik[2], ak[mt][nt][3] * ik[3]);
            qpk[mt][nt] = uq.v; kpk[mt][nt] = uk.v;
        }
    }

    // ---------- attention: 4 heads per wave, all register-resident ----------
    #pragma unroll
    for (int hi = 0; hi < 4; ++hi) {
        const int mt = hi >> 1, par = hi & 1, h = 4 * w + hi;
        const bool keepq = par ? (g >= 2) : (g < 2);
        // V fragment: d=c (c<8), k-token=4g+j; odd heads live at c>=8 -> xor 8
        s16x4 vf[4];
        #pragma unroll
        for (int kv = 0; kv < 4; ++kv) {
            unsigned u0 = vpku[kv][mt][0], u1 = vpku[kv][mt][1];
            if (par) { u0 = (unsigned)__shfl_xor((int)u0, 8); u1 = (unsigned)__shfl_xor((int)u1, 8); }
            BF4 t; t.u[0] = u0; t.u[1] = u1;
            vf[kv] = (c < 8) ? t.v : z4;
        }
        const ushort* bh = biasb + h * 4096;
        #pragma unroll
        for (int tqh = 0; tqh < 2; ++tqh) {
            f32x4 S[4][2];
            #pragma unroll
            for (int t2 = 0; t2 < 2; ++t2) {
                s16x4 qf = keepq ? qpk[mt][2 * tqh + t2] : z4;
                #pragma unroll
                for (int tk = 0; tk < 4; ++tk)
                    S[tk][t2] = __builtin_amdgcn_mfma_f32_16x16x16bf16_1k(kpk[mt][tk], qf, fz, 0, 0, 0);
            }
            float rinv[2];
            #pragma unroll
            for (int t2 = 0; t2 < 2; ++t2) {
                float sum = 0.f;
                #pragma unroll
                for (int tk = 0; tk < 4; ++tk) {
                    ushort4 bv4 = *(const ushort4*)(bh + (16 * (2 * tqh + t2) + c) * 64 + 16 * tk + 4 * g);
                    float e0 = __expf(S[tk][t2][0] + bf2f(bv4.x));
                    float e1 = __expf(S[tk][t2][1] + bf2f(bv4.y));
                    float e2 = __expf(S[tk][t2][2] + bf2f(bv4.z));
                    float e3 = __expf(S[tk][t2][3] + bf2f(bv4.w));
                    S[tk][t2][0] = e0; S[tk][t2][1] = e1;
                    S[tk][t2][2] = e2; S[tk][t2][3] = e3;
                    sum += e0 + e1 + e2 + e3;
                }
                sum += __shfl_xor(sum, 16);
                sum += __shfl_xor(sum, 32);
                rinv[t2] = 1.f / sum;
            }
            #pragma unroll
            for (int t2 = 0; t2 < 2; ++t2) {
                f32x4 o = fz;
                #pragma unroll
                for (int kv = 0; kv < 4; ++kv) {
                    BF4 pa;
                    pa.u[0] = pk2(S[kv][t2][0] * rinv[t2], S[kv][t2][1] * rinv[t2]);
                    pa.u[1] = pk2(S[kv][t2][2] * rinv[t2], S[kv][t2][3] * rinv[t2]);
                    o = __builtin_amdgcn_mfma_f32_16x16x16bf16_1k(pa.v, vf[kv], o, 0, 0, 0);
                }
                if (c < 8) {
                    #pragma unroll
                    for (int j = 0; j < 4; ++j) {
                        int tok = 16 * (2 * tqh + t2) + 4 * g + j;
                        int bo = (tok * 512 + (h * 8 + c) * 2) ^ ((tok & 7) << 4);
                        *(ushort*)((char*)sX + bo) = f2bf(o[j]);
                    }
                }
            }
        }
    }
    __syncthreads();

    // ---------- phase 4: proj GEMM (M=64, N=256, K=256) + bias ----------
    {
        f32x4 pacc[4][2];
        #pragma unroll
        for (int mi = 0; mi < 4; ++mi) { pacc[mi][0] = fz; pacc[mi][1] = fz; }
        #pragma unroll
        for (int ks = 0; ks < 8; ++ks) {
            s16x8 af[4];
            #pragma unroll
            for (int mi = 0; mi < 4; ++mi) {
                int row = 16 * mi + c;
                int bo = (row * 512 + ks * 64 + g * 16) ^ ((row & 7) << 4);
                af[mi] = *(const s16x8*)((const char*)sX + bo);
            }
            s16x8 wfr[2];
            #pragma unroll
            for (int nj = 0; nj < 2; ++nj)
                wfr[nj] = *(const s16x8*)(wp + (32 * w + 16 * nj + c) * 256 + ks * 32 + g * 8);
            #pragma unroll
            for (int mi = 0; mi < 4; ++mi)
                #pragma unroll
                for (int nj = 0; nj < 2; ++nj)
                    pacc[mi][nj] = __builtin_amdgcn_mfma_f32_16x16x32_bf16(af[mi], wfr[nj], pacc[mi][nj], 0, 0, 0);
        }
        float* og = out + (size_t)b * 16384;
        #pragma unroll
        for (int nj = 0; nj < 2; ++nj) {
            int col = 32 * w + 16 * nj + c;
            float bp = bproj[col];
            #pragma unroll
            for (int mi = 0; mi < 4; ++mi)
                #pragma unroll
                for (int j = 0; j < 4; ++j)
                    og[(16 * mi + 4 * g + j) * 256 + col] = pacc[mi][nj][j] + bp;
        }
    }
}

extern "C" void kernel_launch(void* const* d_in, const int* in_sizes, int n_in,
                              void* d_out, int out_size, void* d_ws, size_t ws_size,
                              hipStream_t stream) {
    const float* x     = (const float*)d_in[0];
    const float* wqkv  = (const float*)d_in[1];
    const float* bqkv  = (const float*)d_in[2];
    const float* wproj = (const float*)d_in[3];
    const float* bproj = (const float*)d_in[4];
    const float* btab  = (const float*)d_in[5];

    ushort* wq_b   = (ushort*)d_ws;           // 768*256   = 196608 bf16
    ushort* wp_b   = wq_b + 196608;           // 256*256   =  65536 bf16
    ushort* bias_b = wp_b + 65536;            // 32*64*64  = 131072 bf16 (total 768 KB)

    prep_kernel<<<1536, 256, 0, stream>>>(wqkv, wproj, btab, wq_b, wp_b, bias_b);
    attn_kernel<<<NWIN, 512, 0, stream>>>(x, bqkv, bproj, wq_b, wp_b, bias_b,
                                          (float*)d_out);
}

// Round 3
// 445.100 us; speedup vs baseline: 1.4617x; 1.4617x over previous
//
#include <hip/hip_runtime.h>

typedef __attribute__((ext_vector_type(4))) float f32x4;
typedef __attribute__((ext_vector_type(8))) short s16x8;
typedef __attribute__((ext_vector_type(4))) short s16x4;

// B=2048 windows, N=64 tokens, C=256, H=32 heads, d=8
#define NWIN 2048

__device__ __forceinline__ ushort f2bf(float f) {
    union { float f; unsigned u; } v; v.f = f;
    unsigned r = v.u + 0x7FFFu + ((v.u >> 16) & 1u);   // RNE
    return (ushort)(r >> 16);
}
__device__ __forceinline__ float bf2f(ushort u) {
    union { unsigned u; float f; } v; v.u = ((unsigned)u) << 16;
    return v.f;
}
__device__ __forceinline__ unsigned pk2(float a, float b) {
    return (unsigned)f2bf(a) | ((unsigned)f2bf(b) << 16);
}
union BF4 { unsigned u[2]; s16x4 v; };

// ---- prep: weights -> bf16, bias_table gather -> bias[h][q][k] bf16 ----
__global__ void prep_kernel(const float* __restrict__ wqkv,
                            const float* __restrict__ wproj,
                            const float* __restrict__ btab,
                            ushort* __restrict__ wq,
                            ushort* __restrict__ wp,
                            ushort* __restrict__ bb) {
    int t = blockIdx.x * 256 + threadIdx.x;
    if (t < 196608) {                 // 768*256 w_qkv
        wq[t] = f2bf(wqkv[t]);
    } else if (t < 262144) {          // + 256*256 w_proj
        int i = t - 196608;
        wp[i] = f2bf(wproj[i]);
    } else if (t < 393216) {          // + 32*64*64 bias
        int i = t - 262144;
        int h  = i >> 12;
        int rem = i & 4095;
        int qi = rem >> 6;
        int kj = rem & 63;
        int rh = (qi >> 3) - (kj >> 3) + 7;
        int rw = (qi & 7)  - (kj & 7)  + 7;
        bb[i] = f2bf(btab[(rh * 15 + rw) * 32 + h]);
    }
}

// Fused kernel. Wave w owns heads 4w..4w+3. q/k computed transposed
// (W·x^T) so the GEMM accumulator layout IS the attention fragment layout.
// Register-pressure schedule: V-pass, K-pass(pack bf16 unnorm), Q-pass(pack),
// barrier, normalize packed frags, attention, barrier, proj.
__global__ __launch_bounds__(512, 4) void attn_kernel(
    const float* __restrict__ x,
    const float* __restrict__ bqkv,
    const float* __restrict__ bproj,
    const ushort* __restrict__ wq,
    const ushort* __restrict__ wp,
    const ushort* __restrict__ biasb,
    float* __restrict__ out)
{
    __shared__ ushort sX[64 * 256];   // 32 KB: x bf16 (swizzled), later out_attn
    __shared__ float  sN[1024];       // 4 KB: [0,512) sum q^2 [tok][d]; [512,) k

    const int tid  = threadIdx.x;
    const int lane = tid & 63;
    const int w    = tid >> 6;
    const int g    = lane >> 4;
    const int c    = lane & 15;
    const int b    = blockIdx.x;

    const f32x4 fz = {0.f, 0.f, 0.f, 0.f};
    const s16x4 z4 = {0, 0, 0, 0};

    sN[tid] = 0.f; sN[tid + 512] = 0.f;

    // ---------- stage x -> bf16 LDS (row-XOR swizzled) ----------
    {
        const float4* xg = (const float4*)(x + (size_t)b * 16384);
        #pragma unroll
        for (int it = 0; it < 8; ++it) {
            int i = tid + it * 512;
            float4 v = xg[i];
            int row = i >> 6;
            int col = (i & 63) << 2;
            int bo = (row * 512 + col * 2) ^ ((row & 7) << 4);
            ushort4 u;
            u.x = f2bf(v.x); u.y = f2bf(v.y); u.z = f2bf(v.z); u.w = f2bf(v.w);
            *(ushort4*)((char*)sX + bo) = u;
        }
    }
    __syncthreads();

    // ---------- V-pass: orig orientation GEMM, cols 512+32w..+32 ----------
    s16x4 vpk[4][2];   // token=16kv+4g+j, col=32w+16mt+c
    {
        f32x4 acc[4][2];
        #pragma unroll
        for (int mi = 0; mi < 4; ++mi) { acc[mi][0] = fz; acc[mi][1] = fz; }
        #pragma unroll
        for (int ks = 0; ks < 8; ++ks) {
            s16x8 af[4];
            #pragma unroll
            for (int mi = 0; mi < 4; ++mi) {
                int row = 16 * mi + c;
                int bo = (row * 512 + ks * 64 + g * 16) ^ ((row & 7) << 4);
                af[mi] = *(const s16x8*)((const char*)sX + bo);
            }
            s16x8 wv[2];
            #pragma unroll
            for (int nj = 0; nj < 2; ++nj)
                wv[nj] = *(const s16x8*)(wq + (512 + 32 * w + 16 * nj + c) * 256 + ks * 32 + g * 8);
            #pragma unroll
            for (int mi = 0; mi < 4; ++mi)
                #pragma unroll
                for (int nj = 0; nj < 2; ++nj)
                    acc[mi][nj] = __builtin_amdgcn_mfma_f32_16x16x32_bf16(af[mi], wv[nj], acc[mi][nj], 0, 0, 0);
        }
        #pragma unroll
        for (int nj = 0; nj < 2; ++nj) {
            float bv = bqkv[512 + 32 * w + 16 * nj + c];
            #pragma unroll
            for (int mi = 0; mi < 4; ++mi) {
                BF4 t;
                t.u[0] = pk2(acc[mi][nj][0] + bv, acc[mi][nj][1] + bv);
                t.u[1] = pk2(acc[mi][nj][2] + bv, acc[mi][nj][3] + bv);
                vpk[mi][nj] = t.v;
            }
        }
    }

    // ---------- K-pass: transposed GEMM D = Wk · x^T, pack unnormalized ----------
    s16x4 kpk[2][4];   // [hd-tile mt][token-tile nt]; token=16nt+c, hd=4g+j
    {
        f32x4 ac[2][4];
        #pragma unroll
        for (int mt = 0; mt < 2; ++mt)
            #pragma unroll
            for (int nt = 0; nt < 4; ++nt) ac[mt][nt] = fz;
        #pragma unroll
        for (int ks = 0; ks < 8; ++ks) {
            s16x8 af[4];
            #pragma unroll
            for (int nt = 0; nt < 4; ++nt) {
                int row = 16 * nt + c;
                int bo = (row * 512 + ks * 64 + g * 16) ^ ((row & 7) << 4);
                af[nt] = *(const s16x8*)((const char*)sX + bo);
            }
            s16x8 wk[2];
            #pragma unroll
            for (int mt = 0; mt < 2; ++mt)
                wk[mt] = *(const s16x8*)(wq + (256 + 32 * w + 16 * mt + c) * 256 + ks * 32 + g * 8);
            #pragma unroll
            for (int mt = 0; mt < 2; ++mt)
                #pragma unroll
                for (int nt = 0; nt < 4; ++nt)
                    ac[mt][nt] = __builtin_amdgcn_mfma_f32_16x16x32_bf16(wk[mt], af[nt], ac[mt][nt], 0, 0, 0);
        }
        f32x4 bk0 = *(const f32x4*)(bqkv + 256 + 32 * w + 4 * g);
        f32x4 bk1 = *(const f32x4*)(bqkv + 256 + 32 * w + 16 + 4 * g);
        #pragma unroll
        for (int nt = 0; nt < 4; ++nt) { ac[0][nt] += bk0; ac[1][nt] += bk1; }
        #pragma unroll
        for (int nt = 0; nt < 4; ++nt) {
            #pragma unroll
            for (int j = 0; j < 4; ++j) {
                float p = ac[0][nt][j] * ac[0][nt][j] + ac[1][nt][j] * ac[1][nt][j];
                p += __shfl_xor(p, 32);
                if (g < 2) atomicAdd(&sN[(16 * nt + c) * 8 + 4 * g + j + 512], p);
            }
            #pragma unroll
            for (int mt = 0; mt < 2; ++mt) {
                BF4 t;
                t.u[0] = pk2(ac[mt][nt][0], ac[mt][nt][1]);
                t.u[1] = pk2(ac[mt][nt][2], ac[mt][nt][3]);
                kpk[mt][nt] = t.v;
            }
        }
    }

    // ---------- Q-pass: same, cols 0..256 ----------
    s16x4 qpk[2][4];
    {
        f32x4 ac[2][4];
        #pragma unroll
        for (int mt = 0; mt < 2; ++mt)
            #pragma unroll
            for (int nt = 0; nt < 4; ++nt) ac[mt][nt] = fz;
        #pragma unroll
        for (int ks = 0; ks < 8; ++ks) {
            s16x8 af[4];
            #pragma unroll
            for (int nt = 0; nt < 4; ++nt) {
                int row = 16 * nt + c;
                int bo = (row * 512 + ks * 64 + g * 16) ^ ((row & 7) << 4);
                af[nt] = *(const s16x8*)((const char*)sX + bo);
            }
            s16x8 wqa[2];
            #pragma unroll
            for (int mt = 0; mt < 2; ++mt)
                wqa[mt] = *(const s16x8*)(wq + (32 * w + 16 * mt + c) * 256 + ks * 32 + g * 8);
            #pragma unroll
            for (int mt = 0; mt < 2; ++mt)
                #pragma unroll
                for (int nt = 0; nt < 4; ++nt)
                    ac[mt][nt] = __builtin_amdgcn_mfma_f32_16x16x32_bf16(wqa[mt], af[nt], ac[mt][nt], 0, 0, 0);
        }
        f32x4 bq0 = *(const f32x4*)(bqkv + 32 * w + 4 * g);
        f32x4 bq1 = *(const f32x4*)(bqkv + 32 * w + 16 + 4 * g);
        #pragma unroll
        for (int nt = 0; nt < 4; ++nt) { ac[0][nt] += bq0; ac[1][nt] += bq1; }
        #pragma unroll
        for (int nt = 0; nt < 4; ++nt) {
            #pragma unroll
            for (int j = 0; j < 4; ++j) {
                float p = ac[0][nt][j] * ac[0][nt][j] + ac[1][nt][j] * ac[1][nt][j];
                p += __shfl_xor(p, 32);
                if (g < 2) atomicAdd(&sN[(16 * nt + c) * 8 + 4 * g + j], p);
            }
            #pragma unroll
            for (int mt = 0; mt < 2; ++mt) {
                BF4 t;
                t.u[0] = pk2(ac[mt][nt][0], ac[mt][nt][1]);
                t.u[1] = pk2(ac[mt][nt][2], ac[mt][nt][3]);
                qpk[mt][nt] = t.v;
            }
        }
    }
    __syncthreads();   // norm sums complete; all sX (x) reads complete

    // ---------- normalize packed q/k in place ----------
    #pragma unroll
    for (int nt = 0; nt < 4; ++nt) {
        float iq[4], ik[4];
        #pragma unroll
        for (int j = 0; j < 4; ++j) {
            int a = (16 * nt + c) * 8 + ((4 * g + j) & 7);
            iq[j] = 1.f / fmaxf(sqrtf(sN[a]), 1e-12f);
            ik[j] = 1.f / fmaxf(sqrtf(sN[a + 512]), 1e-12f);
        }
        #pragma unroll
        for (int mt = 0; mt < 2; ++mt) {
            BF4 t; t.v = qpk[mt][nt];
            t.u[0] = pk2(bf2f((ushort)(t.u[0] & 0xffff)) * iq[0],
                         bf2f((ushort)(t.u[0] >> 16))    * iq[1]);
            t.u[1] = pk2(bf2f((ushort)(t.u[1] & 0xffff)) * iq[2],
                         bf2f((ushort)(t.u[1] >> 16))    * iq[3]);
            qpk[mt][nt] = t.v;
            t.v = kpk[mt][nt];
            t.u[0] = pk2(bf2f((ushort)(t.u[0] & 0xffff)) * ik[0],
                         bf2f((ushort)(t.u[0] >> 16))    * ik[1]);
            t.u[1] = pk2(bf2f((ushort)(t.u[1] & 0xffff)) * ik[2],
                         bf2f((ushort)(t.u[1] >> 16))    * ik[3]);
            kpk[mt][nt] = t.v;
        }
    }

    // ---------- attention: 4 heads per wave, register-resident ----------
    #pragma unroll
    for (int hi = 0; hi < 4; ++hi) {
        const int mt = hi >> 1, par = hi & 1, h = 4 * w + hi;
        const bool keepq = par ? (g >= 2) : (g < 2);
        // V fragment: d=c (c<8), k-token=4g+j; odd heads live at c>=8 -> xor 8
        s16x4 vf[4];
        #pragma unroll
        for (int kv = 0; kv < 4; ++kv) {
            BF4 t; t.v = vpk[kv][mt];
            if (par) {
                t.u[0] = (unsigned)__shfl_xor((int)t.u[0], 8);
                t.u[1] = (unsigned)__shfl_xor((int)t.u[1], 8);
            }
            vf[kv] = (c < 8) ? t.v : z4;
        }
        const ushort* bh = biasb + h * 4096;
        #pragma unroll
        for (int tqh = 0; tqh < 2; ++tqh) {
            f32x4 S[4][2];
            #pragma unroll
            for (int t2 = 0; t2 < 2; ++t2) {
                s16x4 qf = keepq ? qpk[mt][2 * tqh + t2] : z4;
                #pragma unroll
                for (int tk = 0; tk < 4; ++tk)
                    S[tk][t2] = __builtin_amdgcn_mfma_f32_16x16x16bf16_1k(kpk[mt][tk], qf, fz, 0, 0, 0);
            }
            float rinv[2];
            #pragma unroll
            for (int t2 = 0; t2 < 2; ++t2) {
                float sum = 0.f;
                #pragma unroll
                for (int tk = 0; tk < 4; ++tk) {
                    ushort4 bv4 = *(const ushort4*)(bh + (16 * (2 * tqh + t2) + c) * 64 + 16 * tk + 4 * g);
                    float e0 = __expf(S[tk][t2][0] + bf2f(bv4.x));
                    float e1 = __expf(S[tk][t2][1] + bf2f(bv4.y));
                    float e2 = __expf(S[tk][t2][2] + bf2f(bv4.z));
                    float e3 = __expf(S[tk][t2][3] + bf2f(bv4.w));
                    S[tk][t2][0] = e0; S[tk][t2][1] = e1;
                    S[tk][t2][2] = e2; S[tk][t2][3] = e3;
                    sum += e0 + e1 + e2 + e3;
                }
                sum += __shfl_xor(sum, 16);
                sum += __shfl_xor(sum, 32);
                rinv[t2] = 1.f / sum;
            }
            #pragma unroll
            for (int t2 = 0; t2 < 2; ++t2) {
                f32x4 o = fz;
                #pragma unroll
                for (int kv = 0; kv < 4; ++kv) {
                    BF4 pa;
                    pa.u[0] = pk2(S[kv][t2][0] * rinv[t2], S[kv][t2][1] * rinv[t2]);
                    pa.u[1] = pk2(S[kv][t2][2] * rinv[t2], S[kv][t2][3] * rinv[t2]);
                    o = __builtin_amdgcn_mfma_f32_16x16x16bf16_1k(pa.v, vf[kv], o, 0, 0, 0);
                }
                if (c < 8) {
                    #pragma unroll
                    for (int j = 0; j < 4; ++j) {
                        int tok = 16 * (2 * tqh + t2) + 4 * g + j;
                        int bo = (tok * 512 + (h * 8 + c) * 2) ^ ((tok & 7) << 4);
                        *(ushort*)((char*)sX + bo) = f2bf(o[j]);
                    }
                }
            }
        }
    }
    __syncthreads();

    // ---------- proj GEMM (M=64, N=256, K=256) + bias ----------
    {
        f32x4 pacc[4][2];
        #pragma unroll
        for (int mi = 0; mi < 4; ++mi) { pacc[mi][0] = fz; pacc[mi][1] = fz; }
        #pragma unroll
        for (int ks = 0; ks < 8; ++ks) {
            s16x8 af[4];
            #pragma unroll
            for (int mi = 0; mi < 4; ++mi) {
                int row = 16 * mi + c;
                int bo = (row * 512 + ks * 64 + g * 16) ^ ((row & 7) << 4);
                af[mi] = *(const s16x8*)((const char*)sX + bo);
            }
            s16x8 wfr[2];
            #pragma unroll
            for (int nj = 0; nj < 2; ++nj)
                wfr[nj] = *(const s16x8*)(wp + (32 * w + 16 * nj + c) * 256 + ks * 32 + g * 8);
            #pragma unroll
            for (int mi = 0; mi < 4; ++mi)
                #pragma unroll
                for (int nj = 0; nj < 2; ++nj)
                    pacc[mi][nj] = __builtin_amdgcn_mfma_f32_16x16x32_bf16(af[mi], wfr[nj], pacc[mi][nj], 0, 0, 0);
        }
        float* og = out + (size_t)b * 16384;
        #pragma unroll
        for (int nj = 0; nj < 2; ++nj) {
            int col = 32 * w + 16 * nj + c;
            float bp = bproj[col];
            #pragma unroll
            for (int mi = 0; mi < 4; ++mi)
                #pragma unroll
                for (int j = 0; j < 4; ++j)
                    og[(16 * mi + 4 * g + j) * 256 + col] = pacc[mi][nj][j] + bp;
        }
    }
}

extern "C" void kernel_launch(void* const* d_in, const int* in_sizes, int n_in,
                              void* d_out, int out_size, void* d_ws, size_t ws_size,
                              hipStream_t stream) {
    const float* x     = (const float*)d_in[0];
    const float* wqkv  = (const float*)d_in[1];
    const float* bqkv  = (const float*)d_in[2];
    const float* wproj = (const float*)d_in[3];
    const float* bproj = (const float*)d_in[4];
    const float* btab  = (const float*)d_in[5];

    ushort* wq_b   = (ushort*)d_ws;           // 768*256   = 196608 bf16
    ushort* wp_b   = wq_b + 196608;           // 256*256   =  65536 bf16
    ushort* bias_b = wp_b + 65536;            // 32*64*64  = 131072 bf16 (total 768 KB)

    prep_kernel<<<1536, 256, 0, stream>>>(wqkv, wproj, btab, wq_b, wp_b, bias_b);
    attn_kernel<<<NWIN, 512, 0, stream>>>(x, bqkv, bproj, wq_b, wp_b, bias_b,
                                          (float*)d_out);
}

// Round 4
// 444.702 us; speedup vs baseline: 1.4630x; 1.0009x over previous
//
#include <hip/hip_runtime.h>

typedef __attribute__((ext_vector_type(4))) float f32x4;
typedef __attribute__((ext_vector_type(8))) short s16x8;
typedef __attribute__((ext_vector_type(4))) short s16x4;

// B=2048 windows, N=64 tokens, C=256, H=32 heads, d=8
#define NWIN 2048

__device__ __forceinline__ ushort f2bf(float f) {
    union { float f; unsigned u; } v; v.f = f;
    unsigned r = v.u + 0x7FFFu + ((v.u >> 16) & 1u);   // RNE
    return (ushort)(r >> 16);
}
__device__ __forceinline__ float bf2f(ushort u) {
    union { unsigned u; float f; } v; v.u = ((unsigned)u) << 16;
    return v.f;
}
__device__ __forceinline__ unsigned pk2(float a, float b) {
    return (unsigned)f2bf(a) | ((unsigned)f2bf(b) << 16);
}
union BF4 { unsigned u[2]; unsigned long long ull; s16x4 v; };

// ---- prep: weights -> bf16, bias_table gather -> bias[h][q][k] bf16 ----
__global__ void prep_kernel(const float* __restrict__ wqkv,
                            const float* __restrict__ wproj,
                            const float* __restrict__ btab,
                            ushort* __restrict__ wq,
                            ushort* __restrict__ wp,
                            ushort* __restrict__ bb) {
    int t = blockIdx.x * 256 + threadIdx.x;
    if (t < 196608) {                 // 768*256 w_qkv
        wq[t] = f2bf(wqkv[t]);
    } else if (t < 262144) {          // + 256*256 w_proj
        int i = t - 196608;
        wp[i] = f2bf(wproj[i]);
    } else if (t < 393216) {          // + 32*64*64 bias
        int i = t - 262144;
        int h  = i >> 12;
        int rem = i & 4095;
        int qi = rem >> 6;
        int kj = rem & 63;
        int rh = (qi >> 3) - (kj >> 3) + 7;
        int rw = (qi & 7)  - (kj & 7)  + 7;
        bb[i] = f2bf(btab[(rh * 15 + rw) * 32 + h]);
    }
}

// Fused kernel. Wave w owns heads 4w..4w+3. q/k computed transposed
// (W·x^T) so the GEMM accumulator layout IS the attention fragment layout.
// V staged to LDS (sV) to keep the register live-set small; S processed
// one q-tile at a time. launch_bounds(512,3): no forced spill; 2 blk/CU
// if allocation lands <=128 total.
__global__ __launch_bounds__(512, 3) void attn_kernel(
    const float* __restrict__ x,
    const float* __restrict__ bqkv,
    const float* __restrict__ bproj,
    const ushort* __restrict__ wq,
    const ushort* __restrict__ wp,
    const ushort* __restrict__ biasb,
    float* __restrict__ out)
{
    __shared__ ushort sX[64 * 256];    // 32 KB: x bf16 (swizzled), later out_attn
    __shared__ ushort sV[32 * 8 * 64]; // 32 KB: V [h][d][tok], swizzled on d
    __shared__ float  sN[1024];        // 4 KB: [0,512) sum q^2 [tok][d]; [512,) k

    const int tid  = threadIdx.x;
    const int lane = tid & 63;
    const int w    = tid >> 6;
    const int g    = lane >> 4;
    const int c    = lane & 15;
    const int b    = blockIdx.x;

    const f32x4 fz = {0.f, 0.f, 0.f, 0.f};
    const s16x4 z4 = {0, 0, 0, 0};

    sN[tid] = 0.f; sN[tid + 512] = 0.f;

    // ---------- stage x -> bf16 LDS (row-XOR swizzled) ----------
    {
        const float4* xg = (const float4*)(x + (size_t)b * 16384);
        #pragma unroll
        for (int it = 0; it < 8; ++it) {
            int i = tid + it * 512;
            float4 v = xg[i];
            int row = i >> 6;
            int col = (i & 63) << 2;
            int bo = (row * 512 + col * 2) ^ ((row & 7) << 4);
            ushort4 u;
            u.x = f2bf(v.x); u.y = f2bf(v.y); u.z = f2bf(v.z); u.w = f2bf(v.w);
            *(ushort4*)((char*)sX + bo) = u;
        }
    }
    __syncthreads();

    // ---------- V-pass: orig orientation GEMM, cols 512+32w..+32 -> sV ----------
    {
        f32x4 acc[4][2];
        #pragma unroll
        for (int mi = 0; mi < 4; ++mi) { acc[mi][0] = fz; acc[mi][1] = fz; }
        #pragma unroll
        for (int ks = 0; ks < 8; ++ks) {
            s16x8 af[4];
            #pragma unroll
            for (int mi = 0; mi < 4; ++mi) {
                int row = 16 * mi + c;
                int bo = (row * 512 + ks * 64 + g * 16) ^ ((row & 7) << 4);
                af[mi] = *(const s16x8*)((const char*)sX + bo);
            }
            s16x8 wv[2];
            #pragma unroll
            for (int nj = 0; nj < 2; ++nj)
                wv[nj] = *(const s16x8*)(wq + (512 + 32 * w + 16 * nj + c) * 256 + ks * 32 + g * 8);
            #pragma unroll
            for (int mi = 0; mi < 4; ++mi)
                #pragma unroll
                for (int nj = 0; nj < 2; ++nj)
                    acc[mi][nj] = __builtin_amdgcn_mfma_f32_16x16x32_bf16(af[mi], wv[nj], acc[mi][nj], 0, 0, 0);
        }
        // epilogue: +bias, pack pairs, ds_write_b64 to sV[h][d][tok] (tok-contig)
        #pragma unroll
        for (int nj = 0; nj < 2; ++nj) {
            int vc = 32 * w + 16 * nj + c;
            float bv = bqkv[512 + vc];
            int hh = vc >> 3, dd = vc & 7;
            #pragma unroll
            for (int mi = 0; mi < 4; ++mi) {
                BF4 t;
                t.u[0] = pk2(acc[mi][nj][0] + bv, acc[mi][nj][1] + bv);
                t.u[1] = pk2(acc[mi][nj][2] + bv, acc[mi][nj][3] + bv);
                int bo = (hh * 1024 + dd * 128 + 32 * mi + 8 * g) ^ (dd << 4);
                *(unsigned long long*)((char*)sV + bo) = t.ull;
            }
        }
    }

    // ---------- K-pass: transposed GEMM D = Wk · x^T, pack unnormalized ----------
    s16x4 kpk[2][4];   // [hd-tile mt][token-tile nt]; token=16nt+c, hd=4g+e
    {
        f32x4 ac[2][4];
        #pragma unroll
        for (int mt = 0; mt < 2; ++mt)
            #pragma unroll
            for (int nt = 0; nt < 4; ++nt) ac[mt][nt] = fz;
        #pragma unroll
        for (int ks = 0; ks < 8; ++ks) {
            s16x8 af[4];
            #pragma unroll
            for (int nt = 0; nt < 4; ++nt) {
                int row = 16 * nt + c;
                int bo = (row * 512 + ks * 64 + g * 16) ^ ((row & 7) << 4);
                af[nt] = *(const s16x8*)((const char*)sX + bo);
            }
            s16x8 wk[2];
            #pragma unroll
            for (int mt = 0; mt < 2; ++mt)
                wk[mt] = *(const s16x8*)(wq + (256 + 32 * w + 16 * mt + c) * 256 + ks * 32 + g * 8);
            #pragma unroll
            for (int mt = 0; mt < 2; ++mt)
                #pragma unroll
                for (int nt = 0; nt < 4; ++nt)
                    ac[mt][nt] = __builtin_amdgcn_mfma_f32_16x16x32_bf16(wk[mt], af[nt], ac[mt][nt], 0, 0, 0);
        }
        f32x4 bk0 = *(const f32x4*)(bqkv + 256 + 32 * w + 4 * g);
        f32x4 bk1 = *(const f32x4*)(bqkv + 256 + 32 * w + 16 + 4 * g);
        #pragma unroll
        for (int nt = 0; nt < 4; ++nt) { ac[0][nt] += bk0; ac[1][nt] += bk1; }
        #pragma unroll
        for (int nt = 0; nt < 4; ++nt) {
            #pragma unroll
            for (int j = 0; j < 4; ++j) {
                float p = ac[0][nt][j] * ac[0][nt][j] + ac[1][nt][j] * ac[1][nt][j];
                p += __shfl_xor(p, 32);
                if (g < 2) atomicAdd(&sN[(16 * nt + c) * 8 + 4 * g + j + 512], p);
            }
            #pragma unroll
            for (int mt = 0; mt < 2; ++mt) {
                BF4 t;
                t.u[0] = pk2(ac[mt][nt][0], ac[mt][nt][1]);
                t.u[1] = pk2(ac[mt][nt][2], ac[mt][nt][3]);
                kpk[mt][nt] = t.v;
            }
        }
    }

    // ---------- Q-pass: same, cols 0..256 ----------
    s16x4 qpk[2][4];
    {
        f32x4 ac[2][4];
        #pragma unroll
        for (int mt = 0; mt < 2; ++mt)
            #pragma unroll
            for (int nt = 0; nt < 4; ++nt) ac[mt][nt] = fz;
        #pragma unroll
        for (int ks = 0; ks < 8; ++ks) {
            s16x8 af[4];
            #pragma unroll
            for (int nt = 0; nt < 4; ++nt) {
                int row = 16 * nt + c;
                int bo = (row * 512 + ks * 64 + g * 16) ^ ((row & 7) << 4);
                af[nt] = *(const s16x8*)((const char*)sX + bo);
            }
            s16x8 wqa[2];
            #pragma unroll
            for (int mt = 0; mt < 2; ++mt)
                wqa[mt] = *(const s16x8*)(wq + (32 * w + 16 * mt + c) * 256 + ks * 32 + g * 8);
            #pragma unroll
            for (int mt = 0; mt < 2; ++mt)
                #pragma unroll
                for (int nt = 0; nt < 4; ++nt)
                    ac[mt][nt] = __builtin_amdgcn_mfma_f32_16x16x32_bf16(wqa[mt], af[nt], ac[mt][nt], 0, 0, 0);
        }
        f32x4 bq0 = *(const f32x4*)(bqkv + 32 * w + 4 * g);
        f32x4 bq1 = *(const f32x4*)(bqkv + 32 * w + 16 + 4 * g);
        #pragma unroll
        for (int nt = 0; nt < 4; ++nt) { ac[0][nt] += bq0; ac[1][nt] += bq1; }
        #pragma unroll
        for (int nt = 0; nt < 4; ++nt) {
            #pragma unroll
            for (int j = 0; j < 4; ++j) {
                float p = ac[0][nt][j] * ac[0][nt][j] + ac[1][nt][j] * ac[1][nt][j];
                p += __shfl_xor(p, 32);
                if (g < 2) atomicAdd(&sN[(16 * nt + c) * 8 + 4 * g + j], p);
            }
            #pragma unroll
            for (int mt = 0; mt < 2; ++mt) {
                BF4 t;
                t.u[0] = pk2(ac[mt][nt][0], ac[mt][nt][1]);
                t.u[1] = pk2(ac[mt][nt][2], ac[mt][nt][3]);
                qpk[mt][nt] = t.v;
            }
        }
    }
    __syncthreads();   // norm sums + sV writes complete; all sX (x) reads done

    // ---------- normalize packed q/k in place ----------
    #pragma unroll
    for (int nt = 0; nt < 4; ++nt) {
        float iq[4], ik[4];
        #pragma unroll
        for (int j = 0; j < 4; ++j) {
            int a = (16 * nt + c) * 8 + ((4 * g + j) & 7);
            iq[j] = 1.f / fmaxf(sqrtf(sN[a]), 1e-12f);
            ik[j] = 1.f / fmaxf(sqrtf(sN[a + 512]), 1e-12f);
        }
        #pragma unroll
        for (int mt = 0; mt < 2; ++mt) {
            BF4 t; t.v = qpk[mt][nt];
            t.u[0] = pk2(bf2f((ushort)(t.u[0] & 0xffff)) * iq[0],
                         bf2f((ushort)(t.u[0] >> 16))    * iq[1]);
            t.u[1] = pk2(bf2f((ushort)(t.u[1] & 0xffff)) * iq[2],
                         bf2f((ushort)(t.u[1] >> 16))    * iq[3]);
            qpk[mt][nt] = t.v;
            t.v = kpk[mt][nt];
            t.u[0] = pk2(bf2f((ushort)(t.u[0] & 0xffff)) * ik[0],
                         bf2f((ushort)(t.u[0] >> 16))    * ik[1]);
            t.u[1] = pk2(bf2f((ushort)(t.u[1] & 0xffff)) * ik[2],
                         bf2f((ushort)(t.u[1] >> 16))    * ik[3]);
            kpk[mt][nt] = t.v;
        }
    }

    // ---------- attention: 4 heads per wave; S one q-tile at a time ----------
    #pragma unroll
    for (int hi = 0; hi < 4; ++hi) {
        const int mt = hi >> 1, par = hi & 1, h = 4 * w + hi;
        const bool keepq = par ? (g >= 2) : (g < 2);
        // V B-fragments from sV: lane (g,c<8) holds V[16kv+4g+e][d=c]
        s16x4 vf[4];
        #pragma unroll
        for (int kv = 0; kv < 4; ++kv) {
            if (c < 8) {
                int bo = (h * 1024 + c * 128 + 32 * kv + 8 * g) ^ (c << 4);
                BF4 t; t.ull = *(const unsigned long long*)((const char*)sV + bo);
                vf[kv] = t.v;
            } else vf[kv] = z4;
        }
        const ushort* bh = biasb + h * 4096;
        #pragma unroll
        for (int tq = 0; tq < 4; ++tq) {
            s16x4 qf = keepq ? qpk[mt][tq] : z4;
            f32x4 S[4];
            #pragma unroll
            for (int tk = 0; tk < 4; ++tk)
                S[tk] = __builtin_amdgcn_mfma_f32_16x16x16bf16_1k(kpk[mt][tk], qf, fz, 0, 0, 0);
            float sum = 0.f;
            #pragma unroll
            for (int tk = 0; tk < 4; ++tk) {
                ushort4 bv4 = *(const ushort4*)(bh + (16 * tq + c) * 64 + 16 * tk + 4 * g);
                float e0 = __expf(S[tk][0] + bf2f(bv4.x));
                float e1 = __expf(S[tk][1] + bf2f(bv4.y));
                float e2 = __expf(S[tk][2] + bf2f(bv4.z));
                float e3 = __expf(S[tk][3] + bf2f(bv4.w));
                S[tk][0] = e0; S[tk][1] = e1; S[tk][2] = e2; S[tk][3] = e3;
                sum += e0 + e1 + e2 + e3;
            }
            sum += __shfl_xor(sum, 16);
            sum += __shfl_xor(sum, 32);
            float rinv = 1.f / sum;
            f32x4 o = fz;
            #pragma unroll
            for (int kv = 0; kv < 4; ++kv) {
                BF4 pa;
                pa.u[0] = pk2(S[kv][0] * rinv, S[kv][1] * rinv);
                pa.u[1] = pk2(S[kv][2] * rinv, S[kv][3] * rinv);
                o = __builtin_amdgcn_mfma_f32_16x16x16bf16_1k(pa.v, vf[kv], o, 0, 0, 0);
            }
            if (c < 8) {
                #pragma unroll
                for (int j = 0; j < 4; ++j) {
                    int tok = 16 * tq + 4 * g + j;
                    int bo = (tok * 512 + (h * 8 + c) * 2) ^ ((tok & 7) << 4);
                    *(ushort*)((char*)sX + bo) = f2bf(o[j]);
                }
            }
        }
    }
    __syncthreads();

    // ---------- proj GEMM (M=64, N=256, K=256) + bias ----------
    {
        f32x4 pacc[4][2];
        #pragma unroll
        for (int mi = 0; mi < 4; ++mi) { pacc[mi][0] = fz; pacc[mi][1] = fz; }
        #pragma unroll
        for (int ks = 0; ks < 8; ++ks) {
            s16x8 af[4];
            #pragma unroll
            for (int mi = 0; mi < 4; ++mi) {
                int row = 16 * mi + c;
                int bo = (row * 512 + ks * 64 + g * 16) ^ ((row & 7) << 4);
                af[mi] = *(const s16x8*)((const char*)sX + bo);
            }
            s16x8 wfr[2];
            #pragma unroll
            for (int nj = 0; nj < 2; ++nj)
                wfr[nj] = *(const s16x8*)(wp + (32 * w + 16 * nj + c) * 256 + ks * 32 + g * 8);
            #pragma unroll
            for (int mi = 0; mi < 4; ++mi)
                #pragma unroll
                for (int nj = 0; nj < 2; ++nj)
                    pacc[mi][nj] = __builtin_amdgcn_mfma_f32_16x16x32_bf16(af[mi], wfr[nj], pacc[mi][nj], 0, 0, 0);
        }
        float* og = out + (size_t)b * 16384;
        #pragma unroll
        for (int nj = 0; nj < 2; ++nj) {
            int col = 32 * w + 16 * nj + c;
            float bp = bproj[col];
            #pragma unroll
            for (int mi = 0; mi < 4; ++mi)
                #pragma unroll
                for (int j = 0; j < 4; ++j)
                    og[(16 * mi + 4 * g + j) * 256 + col] = pacc[mi][nj][j] + bp;
        }
    }
}

extern "C" void kernel_launch(void* const* d_in, const int* in_sizes, int n_in,
                              void* d_out, int out_size, void* d_ws, size_t ws_size,
                              hipStream_t stream) {
    const float* x     = (const float*)d_in[0];
    const float* wqkv  = (const float*)d_in[1];
    const float* bqkv  = (const float*)d_in[2];
    const float* wproj = (const float*)d_in[3];
    const float* bproj = (const float*)d_in[4];
    const float* btab  = (const float*)d_in[5];

    ushort* wq_b   = (ushort*)d_ws;           // 768*256   = 196608 bf16
    ushort* wp_b   = wq_b + 196608;           // 256*256   =  65536 bf16
    ushort* bias_b = wp_b + 65536;            // 32*64*64  = 131072 bf16 (total 768 KB)

    prep_kernel<<<1536, 256, 0, stream>>>(wqkv, wproj, btab, wq_b, wp_b, bias_b);
    attn_kernel<<<NWIN, 512, 0, stream>>>(x, bqkv, bproj, wq_b, wp_b, bias_b,
                                          (float*)d_out);
}

// Round 5
// 436.793 us; speedup vs baseline: 1.4895x; 1.0181x over previous
//
#include <hip/hip_runtime.h>
#include <hip/hip_bf16.h>

typedef __attribute__((ext_vector_type(4))) float f32x4;
typedef __attribute__((ext_vector_type(8))) short s16x8;
typedef __attribute__((ext_vector_type(4))) short s16x4;

// B=2048 windows, N=64 tokens, C=256, H=32 heads, d=8
#define NWIN 2048

__device__ __forceinline__ ushort f2bf(float f) {
    union { __hip_bfloat16 h; ushort u; } v;
    v.h = __float2bfloat16(f);            // HW cvt, RNE
    return v.u;
}
__device__ __forceinline__ float bf2f(ushort u) {
    union { unsigned u; float f; } v; v.u = ((unsigned)u) << 16;
    return v.f;
}
__device__ __forceinline__ unsigned pk2(float a, float b) {
    union { __hip_bfloat162 h; unsigned u; } v;
    v.h = __float22bfloat162_rn(make_float2(a, b));   // v_cvt_pk_bf16_f32
    return v.u;
}
union BF4 { unsigned u[2]; unsigned long long ull; s16x4 v; };

// ---- prep: weights -> bf16, bias_table gather -> bias[h][q][k] bf16 ----
__global__ void prep_kernel(const float* __restrict__ wqkv,
                            const float* __restrict__ wproj,
                            const float* __restrict__ btab,
                            ushort* __restrict__ wq,
                            ushort* __restrict__ wp,
                            ushort* __restrict__ bb) {
    int t = blockIdx.x * 256 + threadIdx.x;
    if (t < 196608) {                 // 768*256 w_qkv
        wq[t] = f2bf(wqkv[t]);
    } else if (t < 262144) {          // + 256*256 w_proj
        int i = t - 196608;
        wp[i] = f2bf(wproj[i]);
    } else if (t < 393216) {          // + 32*64*64 bias
        int i = t - 262144;
        int h  = i >> 12;
        int rem = i & 4095;
        int qi = rem >> 6;
        int kj = rem & 63;
        int rh = (qi >> 3) - (kj >> 3) + 7;
        int rw = (qi & 7)  - (kj & 7)  + 7;
        bb[i] = f2bf(btab[(rh * 15 + rw) * 32 + h]);
    }
}

// Fused kernel. Wave w owns heads 4w..4w+3. q/k computed transposed
// (W·x^T) so the GEMM accumulator layout IS the attention fragment layout.
// V kept in registers (vpk); attention processes one q-tile at a time to
// bound the live set (<128 VGPR total -> 2 blocks/CU with 36 KB LDS).
__global__ __launch_bounds__(512, 4) void attn_kernel(
    const float* __restrict__ x,
    const float* __restrict__ bqkv,
    const float* __restrict__ bproj,
    const ushort* __restrict__ wq,
    const ushort* __restrict__ wp,
    const ushort* __restrict__ biasb,
    float* __restrict__ out)
{
    __shared__ ushort sX[64 * 256];   // 32 KB: x bf16 (swizzled), later out_attn
    __shared__ float  sN[1024];       // 4 KB: [0,512) sum q^2 [tok][d]; [512,) k

    const int tid  = threadIdx.x;
    const int lane = tid & 63;
    const int w    = tid >> 6;
    const int g    = lane >> 4;
    const int c    = lane & 15;
    const int b    = blockIdx.x;

    const f32x4 fz = {0.f, 0.f, 0.f, 0.f};
    const s16x4 z4 = {0, 0, 0, 0};

    sN[tid] = 0.f; sN[tid + 512] = 0.f;

    // ---------- stage x -> bf16 LDS (row-XOR swizzled) ----------
    {
        const float4* xg = (const float4*)(x + (size_t)b * 16384);
        #pragma unroll
        for (int it = 0; it < 8; ++it) {
            int i = tid + it * 512;
            float4 v = xg[i];
            int row = i >> 6;
            int col = (i & 63) << 2;
            int bo = (row * 512 + col * 2) ^ ((row & 7) << 4);
            uint2 u;
            u.x = pk2(v.x, v.y);
            u.y = pk2(v.z, v.w);
            *(uint2*)((char*)sX + bo) = u;
        }
    }
    __syncthreads();

    // ---------- V-pass: orig orientation GEMM, cols 512+32w..+32 ----------
    s16x4 vpk[4][2];   // token=16kv+4g+j, col=32w+16mt+c
    {
        f32x4 acc[4][2];
        #pragma unroll
        for (int mi = 0; mi < 4; ++mi) { acc[mi][0] = fz; acc[mi][1] = fz; }
        #pragma unroll
        for (int ks = 0; ks < 8; ++ks) {
            s16x8 af[4];
            #pragma unroll
            for (int mi = 0; mi < 4; ++mi) {
                int row = 16 * mi + c;
                int bo = (row * 512 + ks * 64 + g * 16) ^ ((row & 7) << 4);
                af[mi] = *(const s16x8*)((const char*)sX + bo);
            }
            s16x8 wv[2];
            #pragma unroll
            for (int nj = 0; nj < 2; ++nj)
                wv[nj] = *(const s16x8*)(wq + (512 + 32 * w + 16 * nj + c) * 256 + ks * 32 + g * 8);
            #pragma unroll
            for (int mi = 0; mi < 4; ++mi)
                #pragma unroll
                for (int nj = 0; nj < 2; ++nj)
                    acc[mi][nj] = __builtin_amdgcn_mfma_f32_16x16x32_bf16(af[mi], wv[nj], acc[mi][nj], 0, 0, 0);
        }
        #pragma unroll
        for (int nj = 0; nj < 2; ++nj) {
            float bv = bqkv[512 + 32 * w + 16 * nj + c];
            #pragma unroll
            for (int mi = 0; mi < 4; ++mi) {
                BF4 t;
                t.u[0] = pk2(acc[mi][nj][0] + bv, acc[mi][nj][1] + bv);
                t.u[1] = pk2(acc[mi][nj][2] + bv, acc[mi][nj][3] + bv);
                vpk[mi][nj] = t.v;
            }
        }
    }

    // ---------- K-pass: transposed GEMM D = Wk · x^T, pack unnormalized ----------
    s16x4 kpk[2][4];   // [hd-tile mt][token-tile nt]; token=16nt+c, hd=4g+e
    {
        f32x4 ac[2][4];
        #pragma unroll
        for (int mt = 0; mt < 2; ++mt)
            #pragma unroll
            for (int nt = 0; nt < 4; ++nt) ac[mt][nt] = fz;
        #pragma unroll
        for (int ks = 0; ks < 8; ++ks) {
            s16x8 af[4];
            #pragma unroll
            for (int nt = 0; nt < 4; ++nt) {
                int row = 16 * nt + c;
                int bo = (row * 512 + ks * 64 + g * 16) ^ ((row & 7) << 4);
                af[nt] = *(const s16x8*)((const char*)sX + bo);
            }
            s16x8 wk[2];
            #pragma unroll
            for (int mt = 0; mt < 2; ++mt)
                wk[mt] = *(const s16x8*)(wq + (256 + 32 * w + 16 * mt + c) * 256 + ks * 32 + g * 8);
            #pragma unroll
            for (int mt = 0; mt < 2; ++mt)
                #pragma unroll
                for (int nt = 0; nt < 4; ++nt)
                    ac[mt][nt] = __builtin_amdgcn_mfma_f32_16x16x32_bf16(wk[mt], af[nt], ac[mt][nt], 0, 0, 0);
        }
        f32x4 bk0 = *(const f32x4*)(bqkv + 256 + 32 * w + 4 * g);
        f32x4 bk1 = *(const f32x4*)(bqkv + 256 + 32 * w + 16 + 4 * g);
        #pragma unroll
        for (int nt = 0; nt < 4; ++nt) { ac[0][nt] += bk0; ac[1][nt] += bk1; }
        #pragma unroll
        for (int nt = 0; nt < 4; ++nt) {
            #pragma unroll
            for (int j = 0; j < 4; ++j) {
                float p = ac[0][nt][j] * ac[0][nt][j] + ac[1][nt][j] * ac[1][nt][j];
                p += __shfl_xor(p, 32);
                if (g < 2) atomicAdd(&sN[(16 * nt + c) * 8 + 4 * g + j + 512], p);
            }
            #pragma unroll
            for (int mt = 0; mt < 2; ++mt) {
                BF4 t;
                t.u[0] = pk2(ac[mt][nt][0], ac[mt][nt][1]);
                t.u[1] = pk2(ac[mt][nt][2], ac[mt][nt][3]);
                kpk[mt][nt] = t.v;
            }
        }
    }

    // ---------- Q-pass: same, cols 0..256 ----------
    s16x4 qpk[2][4];
    {
        f32x4 ac[2][4];
        #pragma unroll
        for (int mt = 0; mt < 2; ++mt)
            #pragma unroll
            for (int nt = 0; nt < 4; ++nt) ac[mt][nt] = fz;
        #pragma unroll
        for (int ks = 0; ks < 8; ++ks) {
            s16x8 af[4];
            #pragma unroll
            for (int nt = 0; nt < 4; ++nt) {
                int row = 16 * nt + c;
                int bo = (row * 512 + ks * 64 + g * 16) ^ ((row & 7) << 4);
                af[nt] = *(const s16x8*)((const char*)sX + bo);
            }
            s16x8 wqa[2];
            #pragma unroll
            for (int mt = 0; mt < 2; ++mt)
                wqa[mt] = *(const s16x8*)(wq + (32 * w + 16 * mt + c) * 256 + ks * 32 + g * 8);
            #pragma unroll
            for (int mt = 0; mt < 2; ++mt)
                #pragma unroll
                for (int nt = 0; nt < 4; ++nt)
                    ac[mt][nt] = __builtin_amdgcn_mfma_f32_16x16x32_bf16(wqa[mt], af[nt], ac[mt][nt], 0, 0, 0);
        }
        f32x4 bq0 = *(const f32x4*)(bqkv + 32 * w + 4 * g);
        f32x4 bq1 = *(const f32x4*)(bqkv + 32 * w + 16 + 4 * g);
        #pragma unroll
        for (int nt = 0; nt < 4; ++nt) { ac[0][nt] += bq0; ac[1][nt] += bq1; }
        #pragma unroll
        for (int nt = 0; nt < 4; ++nt) {
            #pragma unroll
            for (int j = 0; j < 4; ++j) {
                float p = ac[0][nt][j] * ac[0][nt][j] + ac[1][nt][j] * ac[1][nt][j];
                p += __shfl_xor(p, 32);
                if (g < 2) atomicAdd(&sN[(16 * nt + c) * 8 + 4 * g + j], p);
            }
            #pragma unroll
            for (int mt = 0; mt < 2; ++mt) {
                BF4 t;
                t.u[0] = pk2(ac[mt][nt][0], ac[mt][nt][1]);
                t.u[1] = pk2(ac[mt][nt][2], ac[mt][nt][3]);
                qpk[mt][nt] = t.v;
            }
        }
    }
    __syncthreads();   // norm sums complete; all sX (x) reads complete

    // ---------- normalize packed q/k in place ----------
    #pragma unroll
    for (int nt = 0; nt < 4; ++nt) {
        float iq[4], ik[4];
        #pragma unroll
        for (int j = 0; j < 4; ++j) {
            int a = (16 * nt + c) * 8 + ((4 * g + j) & 7);
            iq[j] = 1.f / fmaxf(sqrtf(sN[a]), 1e-12f);
            ik[j] = 1.f / fmaxf(sqrtf(sN[a + 512]), 1e-12f);
        }
        #pragma unroll
        for (int mt = 0; mt < 2; ++mt) {
            BF4 t; t.v = qpk[mt][nt];
            t.u[0] = pk2(bf2f((ushort)(t.u[0] & 0xffff)) * iq[0],
                         bf2f((ushort)(t.u[0] >> 16))    * iq[1]);
            t.u[1] = pk2(bf2f((ushort)(t.u[1] & 0xffff)) * iq[2],
                         bf2f((ushort)(t.u[1] >> 16))    * iq[3]);
            qpk[mt][nt] = t.v;
            t.v = kpk[mt][nt];
            t.u[0] = pk2(bf2f((ushort)(t.u[0] & 0xffff)) * ik[0],
                         bf2f((ushort)(t.u[0] >> 16))    * ik[1]);
            t.u[1] = pk2(bf2f((ushort)(t.u[1] & 0xffff)) * ik[2],
                         bf2f((ushort)(t.u[1] >> 16))    * ik[3]);
            kpk[mt][nt] = t.v;
        }
    }

    // ---------- attention: 4 heads per wave; S one q-tile at a time ----------
    #pragma unroll
    for (int hi = 0; hi < 4; ++hi) {
        const int mt = hi >> 1, par = hi & 1, h = 4 * w + hi;
        const bool keepq = par ? (g >= 2) : (g < 2);
        // V fragment: d=c (c<8), k-token=4g+j; odd heads live at c>=8 -> xor 8
        s16x4 vf[4];
        #pragma unroll
        for (int kv = 0; kv < 4; ++kv) {
            BF4 t; t.v = vpk[kv][mt];
            if (par) {
                t.u[0] = (unsigned)__shfl_xor((int)t.u[0], 8);
                t.u[1] = (unsigned)__shfl_xor((int)t.u[1], 8);
            }
            vf[kv] = (c < 8) ? t.v : z4;
        }
        const ushort* bh = biasb + h * 4096;
        #pragma unroll
        for (int tq = 0; tq < 4; ++tq) {
            s16x4 qf = keepq ? qpk[mt][tq] : z4;
            f32x4 S[4];
            #pragma unroll
            for (int tk = 0; tk < 4; ++tk)
                S[tk] = __builtin_amdgcn_mfma_f32_16x16x16bf16_1k(kpk[mt][tk], qf, fz, 0, 0, 0);
            float sum = 0.f;
            #pragma unroll
            for (int tk = 0; tk < 4; ++tk) {
                ushort4 bv4 = *(const ushort4*)(bh + (16 * tq + c) * 64 + 16 * tk + 4 * g);
                float e0 = __expf(S[tk][0] + bf2f(bv4.x));
                float e1 = __expf(S[tk][1] + bf2f(bv4.y));
                float e2 = __expf(S[tk][2] + bf2f(bv4.z));
                float e3 = __expf(S[tk][3] + bf2f(bv4.w));
                S[tk][0] = e0; S[tk][1] = e1; S[tk][2] = e2; S[tk][3] = e3;
                sum += e0 + e1 + e2 + e3;
            }
            sum += __shfl_xor(sum, 16);
            sum += __shfl_xor(sum, 32);
            float rinv = 1.f / sum;
            f32x4 o = fz;
            #pragma unroll
            for (int kv = 0; kv < 4; ++kv) {
                BF4 pa;
                pa.u[0] = pk2(S[kv][0] * rinv, S[kv][1] * rinv);
                pa.u[1] = pk2(S[kv][2] * rinv, S[kv][3] * rinv);
                o = __builtin_amdgcn_mfma_f32_16x16x16bf16_1k(pa.v, vf[kv], o, 0, 0, 0);
            }
            if (c < 8) {
                #pragma unroll
                for (int j = 0; j < 4; ++j) {
                    int tok = 16 * tq + 4 * g + j;
                    int bo = (tok * 512 + (h * 8 + c) * 2) ^ ((tok & 7) << 4);
                    *(ushort*)((char*)sX + bo) = f2bf(o[j]);
                }
            }
        }
    }
    __syncthreads();

    // ---------- proj GEMM (M=64, N=256, K=256) + bias ----------
    {
        f32x4 pacc[4][2];
        #pragma unroll
        for (int mi = 0; mi < 4; ++mi) { pacc[mi][0] = fz; pacc[mi][1] = fz; }
        #pragma unroll
        for (int ks = 0; ks < 8; ++ks) {
            s16x8 af[4];
            #pragma unroll
            for (int mi = 0; mi < 4; ++mi) {
                int row = 16 * mi + c;
                int bo = (row * 512 + ks * 64 + g * 16) ^ ((row & 7) << 4);
                af[mi] = *(const s16x8*)((const char*)sX + bo);
            }
            s16x8 wfr[2];
            #pragma unroll
            for (int nj = 0; nj < 2; ++nj)
                wfr[nj] = *(const s16x8*)(wp + (32 * w + 16 * nj + c) * 256 + ks * 32 + g * 8);
            #pragma unroll
            for (int mi = 0; mi < 4; ++mi)
                #pragma unroll
                for (int nj = 0; nj < 2; ++nj)
                    pacc[mi][nj] = __builtin_amdgcn_mfma_f32_16x16x32_bf16(af[mi], wfr[nj], pacc[mi][nj], 0, 0, 0);
        }
        float* og = out + (size_t)b * 16384;
        #pragma unroll
        for (int nj = 0; nj < 2; ++nj) {
            int col = 32 * w + 16 * nj + c;
            float bp = bproj[col];
            #pragma unroll
            for (int mi = 0; mi < 4; ++mi)
                #pragma unroll
                for (int j = 0; j < 4; ++j)
                    og[(16 * mi + 4 * g + j) * 256 + col] = pacc[mi][nj][j] + bp;
        }
    }
}

extern "C" void kernel_launch(void* const* d_in, const int* in_sizes, int n_in,
                              void* d_out, int out_size, void* d_ws, size_t ws_size,
                              hipStream_t stream) {
    const float* x     = (const float*)d_in[0];
    const float* wqkv  = (const float*)d_in[1];
    const float* bqkv  = (const float*)d_in[2];
    const float* wproj = (const float*)d_in[3];
    const float* bproj = (const float*)d_in[4];
    const float* btab  = (const float*)d_in[5];

    ushort* wq_b   = (ushort*)d_ws;           // 768*256   = 196608 bf16
    ushort* wp_b   = wq_b + 196608;           // 256*256   =  65536 bf16
    ushort* bias_b = wp_b + 65536;            // 32*64*64  = 131072 bf16 (total 768 KB)

    prep_kernel<<<1536, 256, 0, stream>>>(wqkv, wproj, btab, wq_b, wp_b, bias_b);
    attn_kernel<<<NWIN, 512, 0, stream>>>(x, bqkv, bproj, wq_b, wp_b, bias_b,
                                          (float*)d_out);
}

// Round 6
// 366.664 us; speedup vs baseline: 1.7743x; 1.1913x over previous
//
#include <hip/hip_runtime.h>
#include <hip/hip_bf16.h>

typedef __attribute__((ext_vector_type(4))) float f32x4;
typedef __attribute__((ext_vector_type(8))) short s16x8;
typedef __attribute__((ext_vector_type(4))) short s16x4;

// B=2048 windows, N=64 tokens, C=256, H=32 heads, d=8
#define NWIN 2048

__device__ __forceinline__ ushort f2bf(float f) {
    union { __hip_bfloat16 h; ushort u; } v;
    v.h = __float2bfloat16(f);            // HW cvt, RNE
    return v.u;
}
__device__ __forceinline__ unsigned pk2(float a, float b) {
    union { __hip_bfloat162 h; unsigned u; } v;
    v.h = __float22bfloat162_rn(make_float2(a, b));   // v_cvt_pk_bf16_f32
    return v.u;
}
__device__ __forceinline__ float bf2f(ushort u) {
    union { unsigned u; float f; } v; v.u = ((unsigned)u) << 16;
    return v.f;
}
__device__ __forceinline__ float exp2_hw(float x) {
    float r;
    asm("v_exp_f32 %0, %1" : "=v"(r) : "v"(x));   // v_exp_f32 IS exp2
    return r;
}
union BF4 { unsigned u[2]; unsigned long long ull; s16x4 v; };

#define LOG2E 1.4426950408889634f

// ---- prep: weights -> bf16; bias gather -> f32[h][q][k], pre-scaled by log2e ----
__global__ void prep_kernel(const float* __restrict__ wqkv,
                            const float* __restrict__ wproj,
                            const float* __restrict__ btab,
                            ushort* __restrict__ wq,
                            ushort* __restrict__ wp,
                            float* __restrict__ bf) {
    int t = blockIdx.x * 256 + threadIdx.x;
    if (t < 196608) {                 // 768*256 w_qkv
        wq[t] = f2bf(wqkv[t]);
    } else if (t < 262144) {          // + 256*256 w_proj
        int i = t - 196608;
        wp[i] = f2bf(wproj[i]);
    } else if (t < 393216) {          // + 32*64*64 bias (f32, *log2e)
        int i = t - 262144;
        int h  = i >> 12;
        int rem = i & 4095;
        int qi = rem >> 6;
        int kj = rem & 63;
        int rh = (qi >> 3) - (kj >> 3) + 7;
        int rw = (qi & 7)  - (kj & 7)  + 7;
        bf[i] = btab[(rh * 15 + rw) * 32 + h] * LOG2E;
    }
}

// Fused kernel. Wave w owns heads 4w..4w+3. q/k computed transposed
// (W·x^T) so the GEMM accumulator layout IS the attention fragment layout.
// Natural register allocation (no forced min-waves): zero spill; 2 blk/CU
// if total demand <=128. Softmax via exp2 with log2e folded into q-norm;
// 1/sum applied at the output (P packed unnormalized).
__global__ __launch_bounds__(512) void attn_kernel(
    const float* __restrict__ x,
    const float* __restrict__ bqkv,
    const float* __restrict__ bproj,
    const ushort* __restrict__ wq,
    const ushort* __restrict__ wp,
    const float* __restrict__ biasf,
    float* __restrict__ out)
{
    __shared__ ushort sX[64 * 256];   // 32 KB: x bf16 (swizzled), later out_attn
    __shared__ float  sN[1024];       // 4 KB: [0,512) sum q^2 [tok][d]; [512,) k

    const int tid  = threadIdx.x;
    const int lane = tid & 63;
    const int w    = tid >> 6;
    const int g    = lane >> 4;
    const int c    = lane & 15;
    const int b    = blockIdx.x;

    const f32x4 fz = {0.f, 0.f, 0.f, 0.f};
    const s16x4 z4 = {0, 0, 0, 0};

    sN[tid] = 0.f; sN[tid + 512] = 0.f;

    // ---------- stage x -> bf16 LDS (row-XOR swizzled) ----------
    {
        const float4* xg = (const float4*)(x + (size_t)b * 16384);
        #pragma unroll
        for (int it = 0; it < 8; ++it) {
            int i = tid + it * 512;
            float4 v = xg[i];
            int row = i >> 6;
            int col = (i & 63) << 2;
            int bo = (row * 512 + col * 2) ^ ((row & 7) << 4);
            uint2 u;
            u.x = pk2(v.x, v.y);
            u.y = pk2(v.z, v.w);
            *(uint2*)((char*)sX + bo) = u;
        }
    }
    __syncthreads();

    // ---------- V-pass: orig orientation GEMM, cols 512+32w..+32 ----------
    s16x4 vpk[4][2];   // token=16kv+4g+j, col=32w+16mt+c
    {
        f32x4 acc[4][2];
        #pragma unroll
        for (int mi = 0; mi < 4; ++mi) { acc[mi][0] = fz; acc[mi][1] = fz; }
        #pragma unroll
        for (int ks = 0; ks < 8; ++ks) {
            s16x8 af[4];
            #pragma unroll
            for (int mi = 0; mi < 4; ++mi) {
                int row = 16 * mi + c;
                int bo = (row * 512 + ks * 64 + g * 16) ^ ((row & 7) << 4);
                af[mi] = *(const s16x8*)((const char*)sX + bo);
            }
            s16x8 wv[2];
            #pragma unroll
            for (int nj = 0; nj < 2; ++nj)
                wv[nj] = *(const s16x8*)(wq + (512 + 32 * w + 16 * nj + c) * 256 + ks * 32 + g * 8);
            #pragma unroll
            for (int mi = 0; mi < 4; ++mi)
                #pragma unroll
                for (int nj = 0; nj < 2; ++nj)
                    acc[mi][nj] = __builtin_amdgcn_mfma_f32_16x16x32_bf16(af[mi], wv[nj], acc[mi][nj], 0, 0, 0);
        }
        #pragma unroll
        for (int nj = 0; nj < 2; ++nj) {
            float bv = bqkv[512 + 32 * w + 16 * nj + c];
            #pragma unroll
            for (int mi = 0; mi < 4; ++mi) {
                BF4 t;
                t.u[0] = pk2(acc[mi][nj][0] + bv, acc[mi][nj][1] + bv);
                t.u[1] = pk2(acc[mi][nj][2] + bv, acc[mi][nj][3] + bv);
                vpk[mi][nj] = t.v;
            }
        }
    }

    // ---------- K-pass: transposed GEMM D = Wk · x^T, pack unnormalized ----------
    s16x4 kpk[2][4];   // [hd-tile mt][token-tile nt]; token=16nt+c, hd=4g+e
    {
        f32x4 ac[2][4];
        #pragma unroll
        for (int mt = 0; mt < 2; ++mt)
            #pragma unroll
            for (int nt = 0; nt < 4; ++nt) ac[mt][nt] = fz;
        #pragma unroll
        for (int ks = 0; ks < 8; ++ks) {
            s16x8 af[4];
            #pragma unroll
            for (int nt = 0; nt < 4; ++nt) {
                int row = 16 * nt + c;
                int bo = (row * 512 + ks * 64 + g * 16) ^ ((row & 7) << 4);
                af[nt] = *(const s16x8*)((const char*)sX + bo);
            }
            s16x8 wk[2];
            #pragma unroll
            for (int mt = 0; mt < 2; ++mt)
                wk[mt] = *(const s16x8*)(wq + (256 + 32 * w + 16 * mt + c) * 256 + ks * 32 + g * 8);
            #pragma unroll
            for (int mt = 0; mt < 2; ++mt)
                #pragma unroll
                for (int nt = 0; nt < 4; ++nt)
                    ac[mt][nt] = __builtin_amdgcn_mfma_f32_16x16x32_bf16(wk[mt], af[nt], ac[mt][nt], 0, 0, 0);
        }
        f32x4 bk0 = *(const f32x4*)(bqkv + 256 + 32 * w + 4 * g);
        f32x4 bk1 = *(const f32x4*)(bqkv + 256 + 32 * w + 16 + 4 * g);
        #pragma unroll
        for (int nt = 0; nt < 4; ++nt) { ac[0][nt] += bk0; ac[1][nt] += bk1; }
        #pragma unroll
        for (int nt = 0; nt < 4; ++nt) {
            #pragma unroll
            for (int j = 0; j < 4; ++j) {
                float p = ac[0][nt][j] * ac[0][nt][j] + ac[1][nt][j] * ac[1][nt][j];
                p += __shfl_xor(p, 32);
                if (g < 2) atomicAdd(&sN[(16 * nt + c) * 8 + 4 * g + j + 512], p);
            }
            #pragma unroll
            for (int mt = 0; mt < 2; ++mt) {
                BF4 t;
                t.u[0] = pk2(ac[mt][nt][0], ac[mt][nt][1]);
                t.u[1] = pk2(ac[mt][nt][2], ac[mt][nt][3]);
                kpk[mt][nt] = t.v;
            }
        }
    }

    // ---------- Q-pass: same, cols 0..256 ----------
    s16x4 qpk[2][4];
    {
        f32x4 ac[2][4];
        #pragma unroll
        for (int mt = 0; mt < 2; ++mt)
            #pragma unroll
            for (int nt = 0; nt < 4; ++nt) ac[mt][nt] = fz;
        #pragma unroll
        for (int ks = 0; ks < 8; ++ks) {
            s16x8 af[4];
            #pragma unroll
            for (int nt = 0; nt < 4; ++nt) {
                int row = 16 * nt + c;
                int bo = (row * 512 + ks * 64 + g * 16) ^ ((row & 7) << 4);
                af[nt] = *(const s16x8*)((const char*)sX + bo);
            }
            s16x8 wqa[2];
            #pragma unroll
            for (int mt = 0; mt < 2; ++mt)
                wqa[mt] = *(const s16x8*)(wq + (32 * w + 16 * mt + c) * 256 + ks * 32 + g * 8);
            #pragma unroll
            for (int mt = 0; mt < 2; ++mt)
                #pragma unroll
                for (int nt = 0; nt < 4; ++nt)
                    ac[mt][nt] = __builtin_amdgcn_mfma_f32_16x16x32_bf16(wqa[mt], af[nt], ac[mt][nt], 0, 0, 0);
        }
        f32x4 bq0 = *(const f32x4*)(bqkv + 32 * w + 4 * g);
        f32x4 bq1 = *(const f32x4*)(bqkv + 32 * w + 16 + 4 * g);
        #pragma unroll
        for (int nt = 0; nt < 4; ++nt) { ac[0][nt] += bq0; ac[1][nt] += bq1; }
        #pragma unroll
        for (int nt = 0; nt < 4; ++nt) {
            #pragma unroll
            for (int j = 0; j < 4; ++j) {
                float p = ac[0][nt][j] * ac[0][nt][j] + ac[1][nt][j] * ac[1][nt][j];
                p += __shfl_xor(p, 32);
                if (g < 2) atomicAdd(&sN[(16 * nt + c) * 8 + 4 * g + j], p);
            }
            #pragma unroll
            for (int mt = 0; mt < 2; ++mt) {
                BF4 t;
                t.u[0] = pk2(ac[mt][nt][0], ac[mt][nt][1]);
                t.u[1] = pk2(ac[mt][nt][2], ac[mt][nt][3]);
                qpk[mt][nt] = t.v;
            }
        }
    }
    __syncthreads();   // norm sums complete; all sX (x) reads complete

    // ---------- normalize packed q/k in place (q gets *log2e for exp2) ----------
    #pragma unroll
    for (int nt = 0; nt < 4; ++nt) {
        // lanes g=0,2 need d 0..3; g=1,3 need d 4..7 -> one b128 each
        f32x4 sq = *(const f32x4*)&sN[(16 * nt + c) * 8 + (g & 1) * 4];
        f32x4 sk = *(const f32x4*)&sN[512 + (16 * nt + c) * 8 + (g & 1) * 4];
        float iq[4], ik[4];
        #pragma unroll
        for (int j = 0; j < 4; ++j) {
            iq[j] = LOG2E * __builtin_amdgcn_rcpf(fmaxf(__builtin_amdgcn_sqrtf(sq[j]), 1e-12f));
            ik[j] = __builtin_amdgcn_rcpf(fmaxf(__builtin_amdgcn_sqrtf(sk[j]), 1e-12f));
        }
        #pragma unroll
        for (int mt = 0; mt < 2; ++mt) {
            BF4 t; t.v = qpk[mt][nt];
            t.u[0] = pk2(bf2f((ushort)(t.u[0] & 0xffff)) * iq[0],
                         bf2f((ushort)(t.u[0] >> 16))    * iq[1]);
            t.u[1] = pk2(bf2f((ushort)(t.u[1] & 0xffff)) * iq[2],
                         bf2f((ushort)(t.u[1] >> 16))    * iq[3]);
            qpk[mt][nt] = t.v;
            t.v = kpk[mt][nt];
            t.u[0] = pk2(bf2f((ushort)(t.u[0] & 0xffff)) * ik[0],
                         bf2f((ushort)(t.u[0] >> 16))    * ik[1]);
            t.u[1] = pk2(bf2f((ushort)(t.u[1] & 0xffff)) * ik[2],
                         bf2f((ushort)(t.u[1] >> 16))    * ik[3]);
            kpk[mt][nt] = t.v;
        }
    }

    // ---------- attention: 4 heads per wave; S one q-tile at a time ----------
    #pragma unroll
    for (int hi = 0; hi < 4; ++hi) {
        const int mt = hi >> 1, par = hi & 1, h = 4 * w + hi;
        const bool keepq = par ? (g >= 2) : (g < 2);
        // V fragment: d=c (c<8), k-token=4g+j; odd heads live at c>=8 -> xor 8
        s16x4 vf[4];
        #pragma unroll
        for (int kv = 0; kv < 4; ++kv) {
            BF4 t; t.v = vpk[kv][mt];
            if (par) {
                t.u[0] = (unsigned)__shfl_xor((int)t.u[0], 8);
                t.u[1] = (unsigned)__shfl_xor((int)t.u[1], 8);
            }
            vf[kv] = (c < 8) ? t.v : z4;
        }
        const float* bhf = biasf + h * 4096;
        #pragma unroll
        for (int tq = 0; tq < 4; ++tq) {
            s16x4 qf = keepq ? qpk[mt][tq] : z4;
            f32x4 S[4];
            #pragma unroll
            for (int tk = 0; tk < 4; ++tk)
                S[tk] = __builtin_amdgcn_mfma_f32_16x16x16bf16_1k(kpk[mt][tk], qf, fz, 0, 0, 0);
            float sum = 0.f;
            #pragma unroll
            for (int tk = 0; tk < 4; ++tk) {
                f32x4 bv4 = *(const f32x4*)(bhf + (16 * tq + c) * 64 + 16 * tk + 4 * g);
                S[tk][0] = exp2_hw(S[tk][0] + bv4[0]);
                S[tk][1] = exp2_hw(S[tk][1] + bv4[1]);
                S[tk][2] = exp2_hw(S[tk][2] + bv4[2]);
                S[tk][3] = exp2_hw(S[tk][3] + bv4[3]);
                sum += S[tk][0] + S[tk][1] + S[tk][2] + S[tk][3];
            }
            sum += __shfl_xor(sum, 16);
            sum += __shfl_xor(sum, 32);
            float rinv = __builtin_amdgcn_rcpf(sum);
            f32x4 o = fz;
            #pragma unroll
            for (int kv = 0; kv < 4; ++kv) {
                BF4 pa;
                pa.u[0] = pk2(S[kv][0], S[kv][1]);
                pa.u[1] = pk2(S[kv][2], S[kv][3]);
                o = __builtin_amdgcn_mfma_f32_16x16x16bf16_1k(pa.v, vf[kv], o, 0, 0, 0);
            }
            if (c < 8) {
                #pragma unroll
                for (int j = 0; j < 4; ++j) {
                    int tok = 16 * tq + 4 * g + j;
                    int bo = (tok * 512 + (h * 8 + c) * 2) ^ ((tok & 7) << 4);
                    *(ushort*)((char*)sX + bo) = f2bf(o[j] * rinv);
                }
            }
        }
    }
    __syncthreads();

    // ---------- proj GEMM (M=64, N=256, K=256) + bias ----------
    {
        f32x4 pacc[4][2];
        #pragma unroll
        for (int mi = 0; mi < 4; ++mi) { pacc[mi][0] = fz; pacc[mi][1] = fz; }
        #pragma unroll
        for (int ks = 0; ks < 8; ++ks) {
            s16x8 af[4];
            #pragma unroll
            for (int mi = 0; mi < 4; ++mi) {
                int row = 16 * mi + c;
                int bo = (row * 512 + ks * 64 + g * 16) ^ ((row & 7) << 4);
                af[mi] = *(const s16x8*)((const char*)sX + bo);
            }
            s16x8 wfr[2];
            #pragma unroll
            for (int nj = 0; nj < 2; ++nj)
                wfr[nj] = *(const s16x8*)(wp + (32 * w + 16 * nj + c) * 256 + ks * 32 + g * 8);
            #pragma unroll
            for (int mi = 0; mi < 4; ++mi)
                #pragma unroll
                for (int nj = 0; nj < 2; ++nj)
                    pacc[mi][nj] = __builtin_amdgcn_mfma_f32_16x16x32_bf16(af[mi], wfr[nj], pacc[mi][nj], 0, 0, 0);
        }
        float* og = out + (size_t)b * 16384;
        #pragma unroll
        for (int nj = 0; nj < 2; ++nj) {
            int col = 32 * w + 16 * nj + c;
            float bp = bproj[col];
            #pragma unroll
            for (int mi = 0; mi < 4; ++mi)
                #pragma unroll
                for (int j = 0; j < 4; ++j)
                    og[(16 * mi + 4 * g + j) * 256 + col] = pacc[mi][nj][j] + bp;
        }
    }
}

extern "C" void kernel_launch(void* const* d_in, const int* in_sizes, int n_in,
                              void* d_out, int out_size, void* d_ws, size_t ws_size,
                              hipStream_t stream) {
    const float* x     = (const float*)d_in[0];
    const float* wqkv  = (const float*)d_in[1];
    const float* bqkv  = (const float*)d_in[2];
    const float* wproj = (const float*)d_in[3];
    const float* bproj = (const float*)d_in[4];
    const float* btab  = (const float*)d_in[5];

    ushort* wq_b   = (ushort*)d_ws;                     // 768*256 bf16 = 384 KB
    ushort* wp_b   = wq_b + 196608;                     // 256*256 bf16 = 128 KB
    float*  bias_f = (float*)((char*)d_ws + 524288);    // 32*64*64 f32 = 512 KB

    prep_kernel<<<1536, 256, 0, stream>>>(wqkv, wproj, btab, wq_b, wp_b, bias_f);
    attn_kernel<<<NWIN, 512, 0, stream>>>(x, bqkv, bproj, wq_b, wp_b, bias_f,
                                          (float*)d_out);
}